// Round 7
// baseline (293.997 us; speedup 1.0000x reference)
//
#include <hip/hip_runtime.h>
#include <cstdint>
#include <cstddef>

typedef __bf16 bf16x8 __attribute__((ext_vector_type(8)));
typedef float  f32x4  __attribute__((ext_vector_type(4)));

#define TT 8192
#define EE 1024
#define LDSK 40    // small-path padded LDS stride (shorts)

__device__ __forceinline__ unsigned short f2bf(float f) {
    union { float f; unsigned int u; } v; v.f = f;
    unsigned int r = v.u + 0x7FFFu + ((v.u >> 16) & 1u);
    return (unsigned short)(r >> 16);
}
__device__ __forceinline__ float b2f(unsigned int h) {
    union { unsigned int u; float f; } v; v.u = h << 16; return v.f;
}
__device__ __forceinline__ void gload_lds16(const void* g, void* l) {
    __builtin_amdgcn_global_load_lds((__attribute__((address_space(1))) void*)g,
                                     (__attribute__((address_space(3))) void*)l, 16, 0, 0);
}

// ---------------------------------------------------------------------------
// Standalone W transpose (small path). grid (32,32,4), block (32,8).
// ---------------------------------------------------------------------------
__global__ void wt_kernel(const float* __restrict__ Wk, const float* __restrict__ Wv,
                          const float* __restrict__ Wr, const float* __restrict__ Wo,
                          unsigned short* __restrict__ Tk, unsigned short* __restrict__ Tv,
                          unsigned short* __restrict__ Tr, unsigned short* __restrict__ To) {
    __shared__ float tile[32][33];
    const float* W; unsigned short* D;
    switch (blockIdx.z) {
        case 0:  W = Wk; D = Tk; break;
        case 1:  W = Wv; D = Tv; break;
        case 2:  W = Wr; D = Tr; break;
        default: W = Wo; D = To; break;
    }
    const int bx = blockIdx.x * 32, by = blockIdx.y * 32;
    const int tx = threadIdx.x, ty = threadIdx.y;
#pragma unroll
    for (int r = 0; r < 4; ++r)
        tile[ty + 8 * r][tx] = W[(size_t)(by + ty + 8 * r) * EE + bx + tx];
    __syncthreads();
#pragma unroll
    for (int r = 0; r < 4; ++r)
        D[(size_t)(bx + ty + 8 * r) * EE + by + tx] = f2bf(tile[tx][ty + 8 * r]);
}

// ---------------------------------------------------------------------------
// Fused prep: blocks [0,4096) transpose 4 Ws; blocks [4096,12288) token-shift
// mix -> bf16 kx/vx/rx.  1D grid 12288, block 256.
// ---------------------------------------------------------------------------
__global__ void prep_kernel(const float* __restrict__ Wk, const float* __restrict__ Wv,
                            const float* __restrict__ Wr, const float* __restrict__ Wo,
                            unsigned short* __restrict__ Tk, unsigned short* __restrict__ Tv,
                            unsigned short* __restrict__ Tr, unsigned short* __restrict__ To,
                            const float* __restrict__ x, const float* __restrict__ sx,
                            const float* __restrict__ tmk, const float* __restrict__ tmv,
                            const float* __restrict__ tmr,
                            unsigned short* __restrict__ kxb, unsigned short* __restrict__ vxb,
                            unsigned short* __restrict__ rxb) {
    const int bid = blockIdx.x;
    if (bid < 4096) {
        __shared__ float tile[32][33];
        const int z = bid >> 10;
        const float* W; unsigned short* D;
        switch (z) {
            case 0:  W = Wk; D = Tk; break;
            case 1:  W = Wv; D = Tv; break;
            case 2:  W = Wr; D = Tr; break;
            default: W = Wo; D = To; break;
        }
        const int by = ((bid >> 5) & 31) * 32, bx = (bid & 31) * 32;
        const int tx = threadIdx.x & 31, ty = threadIdx.x >> 5;
#pragma unroll
        for (int r = 0; r < 4; ++r)
            tile[ty + 8 * r][tx] = W[(size_t)(by + ty + 8 * r) * EE + bx + tx];
        __syncthreads();
#pragma unroll
        for (int r = 0; r < 4; ++r)
            D[(size_t)(bx + ty + 8 * r) * EE + by + tx] = f2bf(tile[tx][ty + 8 * r]);
    } else {
        const int gid  = (bid - 4096) * 256 + threadIdx.x;
        const int base = gid * 4;
        const int t = base >> 10;
        const int e = base & (EE - 1);
        float4 xv = *(const float4*)(x + base);
        float4 pv = (t > 0) ? *(const float4*)(x + base - EE) : *(const float4*)(sx + e);
        float4 mk = *(const float4*)(tmk + e);
        float4 mv = *(const float4*)(tmv + e);
        float4 mr = *(const float4*)(tmr + e);
        ushort4 ko, vo, ro;
        ko.x = f2bf(fmaf(mk.x, xv.x - pv.x, pv.x));
        ko.y = f2bf(fmaf(mk.y, xv.y - pv.y, pv.y));
        ko.z = f2bf(fmaf(mk.z, xv.z - pv.z, pv.z));
        ko.w = f2bf(fmaf(mk.w, xv.w - pv.w, pv.w));
        vo.x = f2bf(fmaf(mv.x, xv.x - pv.x, pv.x));
        vo.y = f2bf(fmaf(mv.y, xv.y - pv.y, pv.y));
        vo.z = f2bf(fmaf(mv.z, xv.z - pv.z, pv.z));
        vo.w = f2bf(fmaf(mv.w, xv.w - pv.w, pv.w));
        ro.x = f2bf(fmaf(mr.x, xv.x - pv.x, pv.x));
        ro.y = f2bf(fmaf(mr.y, xv.y - pv.y, pv.y));
        ro.z = f2bf(fmaf(mr.z, xv.z - pv.z, pv.z));
        ro.w = f2bf(fmaf(mr.w, xv.w - pv.w, pv.w));
        *(ushort4*)(kxb + base) = ko;
        *(ushort4*)(vxb + base) = vo;
        *(ushort4*)(rxb + base) = ro;
    }
}

// ---------------------------------------------------------------------------
// Double-buffered 256x128 GEMM, BK=32, single barrier per K-iter.
// Prefetch for tile i+1 issues right after the barrier and lands during
// compute of tile i (explicit vmcnt(0) before the next barrier).
// 3 operand sets via blockIdx.z (z==2 -> sigmoid).  grid (32,8,3).
// ---------------------------------------------------------------------------
__global__ __launch_bounds__(256, 2) void gemm_kvr3_db(
        const unsigned short* __restrict__ kxb, const unsigned short* __restrict__ vxb,
        const unsigned short* __restrict__ rxb,
        const unsigned short* __restrict__ Wkt, const unsigned short* __restrict__ Wvt,
        const unsigned short* __restrict__ Wrt,
        unsigned short* __restrict__ kf, unsigned short* __restrict__ vf,
        unsigned short* __restrict__ ry) {
    __shared__ __align__(16) unsigned short As[2][256 * 32];   // 2 x 16 KB
    __shared__ __align__(16) unsigned short Bs[2][128 * 32];   // 2 x 8 KB
    const int z = blockIdx.z;
    const unsigned short* A  = (z == 0) ? kxb : (z == 1) ? vxb : rxb;
    const unsigned short* Bt = (z == 0) ? Wkt : (z == 1) ? Wvt : Wrt;
    unsigned short* C        = (z == 0) ? kf  : (z == 1) ? vf  : ry;

    const int tid  = threadIdx.x;
    const int wave = tid >> 6, lane = tid & 63;
    const int wm = (wave >> 1) * 128, wn = (wave & 1) * 64;
    const int l15 = lane & 15, lq = lane >> 4;
    const int lrow = lane >> 2, lcol = (lane & 3) * 8;   // 4 lanes/row, 16 rows/instr
    const int bm = blockIdx.x * 256, bn = blockIdx.y * 128;

    f32x4 acc[8][4] = {};

#define STAGE_KVR(kt, dst) {                                                      \
    _Pragma("unroll") for (int p = 0; p < 4; ++p) {                               \
        const int r0 = p * 64 + wave * 16;                                        \
        gload_lds16(A + (size_t)(bm + r0 + lrow) * 1024 + (kt) + lcol,            \
                    &As[dst][r0 * 32]); }                                         \
    _Pragma("unroll") for (int p = 0; p < 2; ++p) {                               \
        const int r0 = p * 64 + wave * 16;                                        \
        gload_lds16(Bt + (size_t)(bn + r0 + lrow) * 1024 + (kt) + lcol,           \
                    &Bs[dst][r0 * 32]); } }

    STAGE_KVR(0, 0);
    for (int it = 0; it < 32; ++it) {
        asm volatile("s_waitcnt vmcnt(0)" ::: "memory");
        __syncthreads();
        const int cur = it & 1;
        if (it < 31) STAGE_KVR((it + 1) * 32, cur ^ 1);
        bf16x8 af[8], bfr[4];
#pragma unroll
        for (int i = 0; i < 8; ++i)
            af[i] = *(const bf16x8*)(&As[cur][(wm + i * 16 + l15) * 32 + lq * 8]);
#pragma unroll
        for (int j = 0; j < 4; ++j)
            bfr[j] = *(const bf16x8*)(&Bs[cur][(wn + j * 16 + l15) * 32 + lq * 8]);
#pragma unroll
        for (int i = 0; i < 8; ++i)
#pragma unroll
            for (int j = 0; j < 4; ++j)
                acc[i][j] = __builtin_amdgcn_mfma_f32_16x16x32_bf16(af[i], bfr[j], acc[i][j], 0, 0, 0);
    }
#undef STAGE_KVR

    const bool sig = (z == 2);
#pragma unroll
    for (int i = 0; i < 8; ++i)
#pragma unroll
        for (int j = 0; j < 4; ++j) {
            const int col = bn + wn + j * 16 + l15;
#pragma unroll
            for (int r = 0; r < 4; ++r) {
                const int row = bm + wm + i * 16 + lq * 4 + r;
                float val = acc[i][j][r];
                if (sig) val = 1.f / (1.f + __expf(-val));
                C[(size_t)row * 1024 + col] = f2bf(val);
            }
        }
}

// ---------------------------------------------------------------------------
// Double-buffered 256x128 Wo GEMM: C f32 = A bf16 @ Bt^T + Res.  grid (32,8).
// ---------------------------------------------------------------------------
__global__ __launch_bounds__(256, 2) void gemm_wo_db(const unsigned short* __restrict__ A,
                                                     const unsigned short* __restrict__ Bt,
                                                     const float* __restrict__ Res,
                                                     float* __restrict__ C) {
    __shared__ __align__(16) unsigned short As[2][256 * 32];
    __shared__ __align__(16) unsigned short Bs[2][128 * 32];
    const int tid  = threadIdx.x;
    const int wave = tid >> 6, lane = tid & 63;
    const int wm = (wave >> 1) * 128, wn = (wave & 1) * 64;
    const int l15 = lane & 15, lq = lane >> 4;
    const int lrow = lane >> 2, lcol = (lane & 3) * 8;
    const int bm = blockIdx.x * 256, bn = blockIdx.y * 128;

    f32x4 acc[8][4] = {};

#define STAGE_WO(kt, dst) {                                                       \
    _Pragma("unroll") for (int p = 0; p < 4; ++p) {                               \
        const int r0 = p * 64 + wave * 16;                                        \
        gload_lds16(A + (size_t)(bm + r0 + lrow) * 1024 + (kt) + lcol,            \
                    &As[dst][r0 * 32]); }                                         \
    _Pragma("unroll") for (int p = 0; p < 2; ++p) {                               \
        const int r0 = p * 64 + wave * 16;                                        \
        gload_lds16(Bt + (size_t)(bn + r0 + lrow) * 1024 + (kt) + lcol,           \
                    &Bs[dst][r0 * 32]); } }

    STAGE_WO(0, 0);
    for (int it = 0; it < 32; ++it) {
        asm volatile("s_waitcnt vmcnt(0)" ::: "memory");
        __syncthreads();
        const int cur = it & 1;
        if (it < 31) STAGE_WO((it + 1) * 32, cur ^ 1);
        bf16x8 af[8], bfr[4];
#pragma unroll
        for (int i = 0; i < 8; ++i)
            af[i] = *(const bf16x8*)(&As[cur][(wm + i * 16 + l15) * 32 + lq * 8]);
#pragma unroll
        for (int j = 0; j < 4; ++j)
            bfr[j] = *(const bf16x8*)(&Bs[cur][(wn + j * 16 + l15) * 32 + lq * 8]);
#pragma unroll
        for (int i = 0; i < 8; ++i)
#pragma unroll
            for (int j = 0; j < 4; ++j)
                acc[i][j] = __builtin_amdgcn_mfma_f32_16x16x32_bf16(af[i], bfr[j], acc[i][j], 0, 0, 0);
    }
#undef STAGE_WO

#pragma unroll
    for (int i = 0; i < 8; ++i)
#pragma unroll
        for (int j = 0; j < 4; ++j) {
            const int col = bn + wn + j * 16 + l15;
#pragma unroll
            for (int r = 0; r < 4; ++r) {
                const int row = bm + wm + i * 16 + lq * 4 + r;
                const size_t idx = (size_t)row * 1024 + col;
                C[idx] = acc[i][j][r] + Res[idx];
            }
        }
}

// ---------------------------------------------------------------------------
// WKV pass A: per (chunk, channel) stabilized local summary.
// NC chunks of length TT/NC.  grid NC*EE/256 x 256.
// ---------------------------------------------------------------------------
template <int NC>
__global__ void wkv_pass_a(const unsigned short* __restrict__ k,
                           const unsigned short* __restrict__ v,
                           const float* __restrict__ td,
                           float* __restrict__ Sa, float* __restrict__ Sb, float* __restrict__ Sp) {
    const int CL = TT / NC;
    const int gid = blockIdx.x * 256 + threadIdx.x;
    const int c = gid >> 10, e = gid & (EE - 1);
    const float w = -__expf(td[e]);
    float sa = 0.f, sb = 0.f, sp = -1e30f;
    const size_t base = (size_t)c * CL * EE + e;
    for (int i = 0; i < CL; ++i) {
        const size_t idx = base + (size_t)i * EE;
        const float kk = b2f(k[idx]), vv = b2f(v[idx]);
        const float q  = fmaf(w, (float)(CL - 1 - i), kk);
        const float p2 = fmaxf(sp, q);
        const float e1 = __expf(sp - p2), e2 = __expf(q - p2);
        sa = fmaf(e1, sa, e2 * vv);
        sb = fmaf(e1, sb, e2);
        sp = p2;
    }
    Sa[gid] = sa; Sb[gid] = sb; Sp[gid] = sp;
}

// ---------------------------------------------------------------------------
// WKV pass B (parallel): Kogge-Stone scan over NC=256 chunk summaries per
// channel.  grid EE blocks x 256 threads (block = one channel).
// ina/inb/inp layout: [e*NC + c] (coalesced stores).
// ---------------------------------------------------------------------------
__global__ void wkv_pass_b_par(const float* __restrict__ aa, const float* __restrict__ bb,
                               const float* __restrict__ pp, const float* __restrict__ td,
                               const float* __restrict__ x,
                               const float* __restrict__ Sa, const float* __restrict__ Sb,
                               const float* __restrict__ Sp,
                               float* __restrict__ ina, float* __restrict__ inb,
                               float* __restrict__ inp, float* __restrict__ outTail) {
    const int NC = 256, CL = TT / NC;
    const int e = blockIdx.x, c = threadIdx.x;
    __shared__ float sA[256], sB[256], sP[256];
    const float w = -__expf(td[e]);

    float a = Sa[c * EE + e], b = Sb[c * EE + e], p = Sp[c * EE + e];

    // inclusive Kogge-Stone: after shift s, element c covers min(c+1, 2s) chunks
    for (int s = 1; s < NC; s <<= 1) {
        sA[c] = a; sB[c] = b; sP[c] = p;
        __syncthreads();
        if (c >= s) {
            const float myLen = (float)(CL * min(c + 1, s));   // my span before this step
            const float aL = sA[c - s], bL = sB[c - s], pL = sP[c - s];
            const float pLd = pL + w * myLen;
            const float pn  = fmaxf(pLd, p);
            const float e1  = __expf(pLd - pn), e2 = __expf(p - pn);
            a = fmaf(e1, aL, e2 * a);
            b = fmaf(e1, bL, e2 * b);
            p = pn;
        }
        __syncthreads();
    }

    // share inclusive results
    sA[c] = a; sB[c] = b; sP[c] = p;
    __syncthreads();

    const float a0 = aa[e], b0 = bb[e], p0 = pp[e];
    float ea, eb, ep;
    if (c == 0) { ea = a0; eb = b0; ep = p0; }
    else {
        const float aL = sA[c - 1], bL = sB[c - 1], pL = sP[c - 1];  // len = c*CL
        const float p0d = p0 + w * (float)(c * CL);
        const float pn  = fmaxf(p0d, pL);
        const float e1  = __expf(p0d - pn), e2 = __expf(pL - pn);
        ea = fmaf(e1, a0, e2 * aL);
        eb = fmaf(e1, b0, e2 * bL);
        ep = pn;
    }
    ina[e * NC + c] = ea; inb[e * NC + c] = eb; inp[e * NC + c] = ep;

    if (c == NC - 1) {
        // final state: Init over full TT combined with inclusive[0..NC-1]
        const float p0d = p0 + w * (float)TT;
        const float pn  = fmaxf(p0d, p);
        const float e1  = __expf(p0d - pn), e2 = __expf(p - pn);
        outTail[e]          = x[(size_t)(TT - 1) * EE + e];
        outTail[EE + e]     = fmaf(e1, a0, e2 * a);
        outTail[2 * EE + e] = fmaf(e1, b0, e2 * b);
        outTail[3 * EE + e] = pn;
    }
}

// ---------------------------------------------------------------------------
// WKV pass C: replay chunks from incoming state (ina layout [e*NC+c]);
// ry = sigmoid(r) in, y = sigmoid(r)*wkv out (in place).  grid NC*EE/256.
// ---------------------------------------------------------------------------
template <int NC>
__global__ void wkv_pass_c(const unsigned short* __restrict__ k,
                           const unsigned short* __restrict__ v,
                           const float* __restrict__ tf, const float* __restrict__ td,
                           const float* __restrict__ ina, const float* __restrict__ inb,
                           const float* __restrict__ inp,
                           unsigned short* ry) {
    const int CL = TT / NC;
    const int gid = blockIdx.x * 256 + threadIdx.x;
    const int c = gid >> 10, e = gid & (EE - 1);
    const float w = -__expf(td[e]);
    const float u = tf[e];
    float a = ina[e * NC + c], b = inb[e * NC + c], p = inp[e * NC + c];
    const size_t base = (size_t)c * CL * EE + e;
    for (int i = 0; i < CL; ++i) {
        const size_t idx = base + (size_t)i * EE;
        const float kk = b2f(k[idx]), vv = b2f(v[idx]);
        const float rr = b2f(ry[idx]);
        const float ww = u + kk;
        const float pq = fmaxf(p, ww);
        const float e1 = __expf(p - pq), e2 = __expf(ww - pq);
        const float wkv = fmaf(e1, a, e2 * vv) / fmaf(e1, b, e2);
        ry[idx] = f2bf(rr * wkv);
        const float ww2 = w + p;
        const float p2  = fmaxf(ww2, kk);
        const float e1b = __expf(ww2 - p2), e2b = __expf(kk - p2);
        a = fmaf(e1b, a, e2b * vv);
        b = fmaf(e1b, b, e2b);
        p = p2;
    }
}

// ---------------------------------------------------------------------------
// SMALL-path serial pass B (NC=128), ina layout [e*NC+c].
// ---------------------------------------------------------------------------
__global__ void wkv_pass_b_small(const float* __restrict__ aa, const float* __restrict__ bb,
                                 const float* __restrict__ pp, const float* __restrict__ td,
                                 const float* __restrict__ x,
                                 const float* __restrict__ Sa, const float* __restrict__ Sb,
                                 const float* __restrict__ Sp,
                                 float* __restrict__ ina, float* __restrict__ inb,
                                 float* __restrict__ inp, float* __restrict__ outTail) {
    const int NC = 128, CL = TT / NC;
    const int e = blockIdx.x * 256 + threadIdx.x;
    const float w  = -__expf(td[e]);
    const float wL = w * (float)CL;
    float a = aa[e], b = bb[e], p = pp[e];
    for (int c = 0; c < NC; ++c) {
        ina[e * NC + c] = a; inb[e * NC + c] = b; inp[e * NC + c] = p;
        const int idx = c * EE + e;
        const float sa = Sa[idx], sb = Sb[idx], sp = Sp[idx];
        const float pw = p + wL;
        const float p2 = fmaxf(pw, sp);
        const float e1 = __expf(pw - p2), e2 = __expf(sp - p2);
        a = fmaf(e1, a, e2 * sa);
        b = fmaf(e1, b, e2 * sb);
        p = p2;
    }
    outTail[e]          = x[(size_t)(TT - 1) * EE + e];
    outTail[EE + e]     = a;
    outTail[2 * EE + e] = b;
    outTail[3 * EE + e] = p;
}

// ---------------------------------------------------------------------------
// SMALL path (<59 MB): fused-mix k/v/r GEMM (round-3 structure).
// ---------------------------------------------------------------------------
__global__ __launch_bounds__(256, 4) void gemm_kvr(
        const float* __restrict__ X, const float* __restrict__ SX,
        const float* __restrict__ tmk, const float* __restrict__ tmv,
        const float* __restrict__ tmr,
        const unsigned short* __restrict__ Wkt, const unsigned short* __restrict__ Wvt,
        const unsigned short* __restrict__ Wrt,
        unsigned short* __restrict__ outK, unsigned short* __restrict__ outV,
        unsigned short* __restrict__ outR) {
    __shared__ __align__(16) unsigned short As[128 * LDSK];
    __shared__ __align__(16) unsigned short Bs[128 * LDSK];
    const int z = blockIdx.z;
    const float* TM = (z == 0) ? tmk : (z == 1) ? tmv : tmr;
    const unsigned short* Bt = (z == 0) ? Wkt : (z == 1) ? Wvt : Wrt;
    unsigned short* Cout = (z == 0) ? outK : (z == 1) ? outV : outR;

    const int tid  = threadIdx.x;
    const int wave = tid >> 6, lane = tid & 63;
    const int wm = (wave >> 1) * 64, wn = (wave & 1) * 64;
    const int l15 = lane & 15, lq = lane >> 4;
    const int bm = blockIdx.x * 128, bn = blockIdx.y * 128;

    f32x4 acc[4][4] = {};

    for (int kt = 0; kt < 1024; kt += 32) {
        __syncthreads();
#pragma unroll
        for (int p = 0; p < 2; ++p) {
            const int li  = p * 256 + tid;
            const int row = li >> 2, q = li & 3;
            const int e0  = kt + q * 8;
            {
                const int t = bm + row;
                const float* xr = X + (size_t)t * EE + e0;
                const float* pr = (t > 0) ? (X + (size_t)(t - 1) * EE + e0) : (SX + e0);
                float4 xa = *(const float4*)xr, xb = *(const float4*)(xr + 4);
                float4 pa = *(const float4*)pr, pb = *(const float4*)(pr + 4);
                float4 ma = *(const float4*)(TM + e0), mb = *(const float4*)(TM + e0 + 4);
                ushort4 lo, hi;
                lo.x = f2bf(fmaf(ma.x, xa.x - pa.x, pa.x));
                lo.y = f2bf(fmaf(ma.y, xa.y - pa.y, pa.y));
                lo.z = f2bf(fmaf(ma.z, xa.z - pa.z, pa.z));
                lo.w = f2bf(fmaf(ma.w, xa.w - pa.w, pa.w));
                hi.x = f2bf(fmaf(mb.x, xb.x - pb.x, pb.x));
                hi.y = f2bf(fmaf(mb.y, xb.y - pb.y, pb.y));
                hi.z = f2bf(fmaf(mb.z, xb.z - pb.z, pb.z));
                hi.w = f2bf(fmaf(mb.w, xb.w - pb.w, pb.w));
                *(ushort4*)(&As[row * LDSK + q * 8])     = lo;
                *(ushort4*)(&As[row * LDSK + q * 8 + 4]) = hi;
            }
            *(uint4*)(&Bs[row * LDSK + q * 8]) =
                *(const uint4*)(Bt + (size_t)(bn + row) * 1024 + e0);
        }
        __syncthreads();
        bf16x8 af[4], bfr[4];
#pragma unroll
        for (int i = 0; i < 4; ++i) {
            af[i]  = *(const bf16x8*)(&As[(wm + i * 16 + l15) * LDSK + lq * 8]);
            bfr[i] = *(const bf16x8*)(&Bs[(wn + i * 16 + l15) * LDSK + lq * 8]);
        }
#pragma unroll
        for (int i = 0; i < 4; ++i)
#pragma unroll
            for (int j = 0; j < 4; ++j)
                acc[i][j] = __builtin_amdgcn_mfma_f32_16x16x32_bf16(af[i], bfr[j], acc[i][j], 0, 0, 0);
    }

    const bool sig = (z == 2);
#pragma unroll
    for (int i = 0; i < 4; ++i)
#pragma unroll
        for (int j = 0; j < 4; ++j) {
            const int col = bn + wn + j * 16 + l15;
#pragma unroll
            for (int r = 0; r < 4; ++r) {
                const int row = bm + wm + i * 16 + lq * 4 + r;
                float val = acc[i][j][r];
                if (sig) val = 1.f / (1.f + __expf(-val));
                Cout[(size_t)row * 1024 + col] = f2bf(val);
            }
        }
}

// ---------------------------------------------------------------------------
extern "C" void kernel_launch(void* const* d_in, const int* in_sizes, int n_in,
                              void* d_out, int out_size, void* d_ws, size_t ws_size,
                              hipStream_t stream) {
    const float* x   = (const float*)d_in[0];
    const float* sx  = (const float*)d_in[1];
    const float* aa  = (const float*)d_in[2];
    const float* bb  = (const float*)d_in[3];
    const float* pp  = (const float*)d_in[4];
    const float* tf  = (const float*)d_in[5];
    const float* td  = (const float*)d_in[6];
    const float* tmk = (const float*)d_in[7];
    const float* tmv = (const float*)d_in[8];
    const float* tmr = (const float*)d_in[9];
    const float* Wk  = (const float*)d_in[10];
    const float* Wv  = (const float*)d_in[11];
    const float* Wr  = (const float*)d_in[12];
    const float* Wo  = (const float*)d_in[13];
    float* out = (float*)d_out;

    char* ws = (char*)d_ws;
    const size_t MB = 1ull << 20;

    unsigned short* Wkt = (unsigned short*)(ws + 0 * MB);   // 2 MB each
    unsigned short* Wvt = (unsigned short*)(ws + 2 * MB);
    unsigned short* Wrt = (unsigned short*)(ws + 4 * MB);
    unsigned short* Wot = (unsigned short*)(ws + 6 * MB);

    if (ws_size >= 75 * MB) {
        // ws: [0:8] Wt | [8:24] rxb (scan bufs overlay after kvr3) |
        //     [24:40] kf | [40:56] ry | [56:72] vf
        unsigned short* rxb = (unsigned short*)(ws + 8 * MB);
        unsigned short* kf  = (unsigned short*)(ws + 24 * MB);
        unsigned short* ry  = (unsigned short*)(ws + 40 * MB);
        unsigned short* vf  = (unsigned short*)(ws + 56 * MB);
        // scan buffers: 6 x 1 MB, overlaying the dead rxb region [8:14]
        float* Sa  = (float*)(ws + 8 * MB);
        float* Sb  = (float*)(ws + 9 * MB);
        float* Sp  = (float*)(ws + 10 * MB);
        float* ina = (float*)(ws + 11 * MB);
        float* inb = (float*)(ws + 12 * MB);
        float* inp = (float*)(ws + 13 * MB);
        unsigned short* kxb = (unsigned short*)d_out;                   // d_out scratch
        unsigned short* vxb = (unsigned short*)d_out + (size_t)TT * EE;

        prep_kernel<<<12288, 256, 0, stream>>>(Wk, Wv, Wr, Wo, Wkt, Wvt, Wrt, Wot,
                                               x, sx, tmk, tmv, tmr, kxb, vxb, rxb);
        gemm_kvr3_db<<<dim3(32, 8, 3), 256, 0, stream>>>(kxb, vxb, rxb, Wkt, Wvt, Wrt,
                                                         kf, vf, ry);
        wkv_pass_a<256><<<(256 * EE) / 256, 256, 0, stream>>>(kf, vf, td, Sa, Sb, Sp);
        wkv_pass_b_par<<<EE, 256, 0, stream>>>(aa, bb, pp, td, x, Sa, Sb, Sp,
                                               ina, inb, inp, out + (size_t)TT * EE);
        wkv_pass_c<256><<<(256 * EE) / 256, 256, 0, stream>>>(kf, vf, tf, td,
                                                              ina, inb, inp, ry);
        gemm_wo_db<<<dim3(32, 8), 256, 0, stream>>>(ry, Wot, x, out);
    } else {
        // 27 MB proven fallback (NC=128)
        unsigned short* ry = (unsigned short*)(ws + 8 * MB);
        char* scan = ws + 24 * MB;
        const size_t QK = (size_t)128 * EE * sizeof(float);  // 512 KB
        float* Sa  = (float*)(scan);
        float* Sb  = (float*)(scan + QK);
        float* Sp  = (float*)(scan + 2 * QK);
        float* ina = (float*)(scan + 3 * QK);
        float* inb = (float*)(scan + 4 * QK);
        float* inp = (float*)(scan + 5 * QK);
        unsigned short* kf = (unsigned short*)d_out;
        unsigned short* vf = (unsigned short*)d_out + (size_t)TT * EE;

        wt_kernel<<<dim3(32, 32, 4), dim3(32, 8), 0, stream>>>(Wk, Wv, Wr, Wo, Wkt, Wvt, Wrt, Wot);
        gemm_kvr<<<dim3(64, 8, 3), 256, 0, stream>>>(x, sx, tmk, tmv, tmr,
                                                     Wkt, Wvt, Wrt, kf, vf, ry);
        wkv_pass_a<128><<<(128 * EE) / 256, 256, 0, stream>>>(kf, vf, td, Sa, Sb, Sp);
        wkv_pass_b_small<<<4, 256, 0, stream>>>(aa, bb, pp, td, x, Sa, Sb, Sp,
                                                ina, inb, inp, out + (size_t)TT * EE);
        wkv_pass_c<128><<<(128 * EE) / 256, 256, 0, stream>>>(kf, vf, tf, td,
                                                              ina, inb, inp, ry);
        gemm_wo_db<<<dim3(32, 8), 256, 0, stream>>>(ry, Wot, x, out);
    }
}

// Round 8
// 253.406 us; speedup vs baseline: 1.1602x; 1.1602x over previous
//
#include <hip/hip_runtime.h>
#include <cstdint>
#include <cstddef>

typedef __bf16 bf16x8 __attribute__((ext_vector_type(8)));
typedef float  f32x4  __attribute__((ext_vector_type(4)));

#define TT 8192
#define EE 1024
#define LDSK 40    // small-path padded LDS stride (shorts)

__device__ __forceinline__ unsigned short f2bf(float f) {
    union { float f; unsigned int u; } v; v.f = f;
    unsigned int r = v.u + 0x7FFFu + ((v.u >> 16) & 1u);
    return (unsigned short)(r >> 16);
}
__device__ __forceinline__ float b2f(unsigned int h) {
    union { unsigned int u; float f; } v; v.u = h << 16; return v.f;
}
__device__ __forceinline__ void gload_lds16(const void* g, void* l) {
    __builtin_amdgcn_global_load_lds((__attribute__((address_space(1))) void*)g,
                                     (__attribute__((address_space(3))) void*)l, 16, 0, 0);
}

// ---------------------------------------------------------------------------
// Standalone W transpose (small path). grid (32,32,4), block (32,8).
// ---------------------------------------------------------------------------
__global__ void wt_kernel(const float* __restrict__ Wk, const float* __restrict__ Wv,
                          const float* __restrict__ Wr, const float* __restrict__ Wo,
                          unsigned short* __restrict__ Tk, unsigned short* __restrict__ Tv,
                          unsigned short* __restrict__ Tr, unsigned short* __restrict__ To) {
    __shared__ float tile[32][33];
    const float* W; unsigned short* D;
    switch (blockIdx.z) {
        case 0:  W = Wk; D = Tk; break;
        case 1:  W = Wv; D = Tv; break;
        case 2:  W = Wr; D = Tr; break;
        default: W = Wo; D = To; break;
    }
    const int bx = blockIdx.x * 32, by = blockIdx.y * 32;
    const int tx = threadIdx.x, ty = threadIdx.y;
#pragma unroll
    for (int r = 0; r < 4; ++r)
        tile[ty + 8 * r][tx] = W[(size_t)(by + ty + 8 * r) * EE + bx + tx];
    __syncthreads();
#pragma unroll
    for (int r = 0; r < 4; ++r)
        D[(size_t)(bx + ty + 8 * r) * EE + by + tx] = f2bf(tile[tx][ty + 8 * r]);
}

// ---------------------------------------------------------------------------
// Fused prep: blocks [0,4096) transpose 4 Ws; blocks [4096,12288) token-shift
// mix -> bf16 kx/vx/rx.  1D grid 12288, block 256.
// ---------------------------------------------------------------------------
__global__ void prep_kernel(const float* __restrict__ Wk, const float* __restrict__ Wv,
                            const float* __restrict__ Wr, const float* __restrict__ Wo,
                            unsigned short* __restrict__ Tk, unsigned short* __restrict__ Tv,
                            unsigned short* __restrict__ Tr, unsigned short* __restrict__ To,
                            const float* __restrict__ x, const float* __restrict__ sx,
                            const float* __restrict__ tmk, const float* __restrict__ tmv,
                            const float* __restrict__ tmr,
                            unsigned short* __restrict__ kxb, unsigned short* __restrict__ vxb,
                            unsigned short* __restrict__ rxb) {
    const int bid = blockIdx.x;
    if (bid < 4096) {
        __shared__ float tile[32][33];
        const int z = bid >> 10;
        const float* W; unsigned short* D;
        switch (z) {
            case 0:  W = Wk; D = Tk; break;
            case 1:  W = Wv; D = Tv; break;
            case 2:  W = Wr; D = Tr; break;
            default: W = Wo; D = To; break;
        }
        const int by = ((bid >> 5) & 31) * 32, bx = (bid & 31) * 32;
        const int tx = threadIdx.x & 31, ty = threadIdx.x >> 5;
#pragma unroll
        for (int r = 0; r < 4; ++r)
            tile[ty + 8 * r][tx] = W[(size_t)(by + ty + 8 * r) * EE + bx + tx];
        __syncthreads();
#pragma unroll
        for (int r = 0; r < 4; ++r)
            D[(size_t)(bx + ty + 8 * r) * EE + by + tx] = f2bf(tile[tx][ty + 8 * r]);
    } else {
        const int gid  = (bid - 4096) * 256 + threadIdx.x;
        const int base = gid * 4;
        const int t = base >> 10;
        const int e = base & (EE - 1);
        float4 xv = *(const float4*)(x + base);
        float4 pv = (t > 0) ? *(const float4*)(x + base - EE) : *(const float4*)(sx + e);
        float4 mk = *(const float4*)(tmk + e);
        float4 mv = *(const float4*)(tmv + e);
        float4 mr = *(const float4*)(tmr + e);
        ushort4 ko, vo, ro;
        ko.x = f2bf(fmaf(mk.x, xv.x - pv.x, pv.x));
        ko.y = f2bf(fmaf(mk.y, xv.y - pv.y, pv.y));
        ko.z = f2bf(fmaf(mk.z, xv.z - pv.z, pv.z));
        ko.w = f2bf(fmaf(mk.w, xv.w - pv.w, pv.w));
        vo.x = f2bf(fmaf(mv.x, xv.x - pv.x, pv.x));
        vo.y = f2bf(fmaf(mv.y, xv.y - pv.y, pv.y));
        vo.z = f2bf(fmaf(mv.z, xv.z - pv.z, pv.z));
        vo.w = f2bf(fmaf(mv.w, xv.w - pv.w, pv.w));
        ro.x = f2bf(fmaf(mr.x, xv.x - pv.x, pv.x));
        ro.y = f2bf(fmaf(mr.y, xv.y - pv.y, pv.y));
        ro.z = f2bf(fmaf(mr.z, xv.z - pv.z, pv.z));
        ro.w = f2bf(fmaf(mr.w, xv.w - pv.w, pv.w));
        *(ushort4*)(kxb + base) = ko;
        *(ushort4*)(vxb + base) = vo;
        *(ushort4*)(rxb + base) = ro;
    }
}

// ---------------------------------------------------------------------------
// 128x128-tile bf16 GEMM, BK=64, 2-barrier K-loop (16 iters), 3 operand sets
// via blockIdx.z (z==2 -> sigmoid).  grid (64,8,3) = 1536 blocks (~5/CU).
// acc = 4x4 f32x4 (64 AGPR) -> launch_bounds(256,4) for 4-5 resident blocks.
// ---------------------------------------------------------------------------
__global__ __launch_bounds__(256, 4) void gemm_kvr3(
        const unsigned short* __restrict__ kxb, const unsigned short* __restrict__ vxb,
        const unsigned short* __restrict__ rxb,
        const unsigned short* __restrict__ Wkt, const unsigned short* __restrict__ Wvt,
        const unsigned short* __restrict__ Wrt,
        unsigned short* __restrict__ kf, unsigned short* __restrict__ vf,
        unsigned short* __restrict__ ry) {
    __shared__ __align__(16) unsigned short As[128 * 64];   // 16 KB
    __shared__ __align__(16) unsigned short Bs[128 * 64];   // 16 KB
    const int z = blockIdx.z;
    const unsigned short* A  = (z == 0) ? kxb : (z == 1) ? vxb : rxb;
    const unsigned short* Bt = (z == 0) ? Wkt : (z == 1) ? Wvt : Wrt;
    unsigned short* C        = (z == 0) ? kf  : (z == 1) ? vf  : ry;

    const int tid  = threadIdx.x;
    const int wave = tid >> 6, lane = tid & 63;
    const int wm = (wave >> 1) * 64, wn = (wave & 1) * 64;
    const int l15 = lane & 15, lq = lane >> 4;
    const int lrow = lane >> 3, lcol = (lane & 7) * 8;   // 8 lanes/row, 8 rows/instr
    const int bm = blockIdx.x * 128, bn = blockIdx.y * 128;

    f32x4 acc[4][4] = {};

    for (int kt = 0; kt < 1024; kt += 64) {
        __syncthreads();
#pragma unroll
        for (int p = 0; p < 4; ++p) {
            const int r0 = p * 32 + wave * 8;
            gload_lds16(A  + (size_t)(bm + r0 + lrow) * 1024 + kt + lcol, &As[r0 * 64]);
            gload_lds16(Bt + (size_t)(bn + r0 + lrow) * 1024 + kt + lcol, &Bs[r0 * 64]);
        }
        __syncthreads();
#pragma unroll
        for (int h = 0; h < 2; ++h) {
            bf16x8 af[4], bfr[4];
#pragma unroll
            for (int i = 0; i < 4; ++i) {
                af[i]  = *(const bf16x8*)(&As[(wm + i * 16 + l15) * 64 + h * 32 + lq * 8]);
                bfr[i] = *(const bf16x8*)(&Bs[(wn + i * 16 + l15) * 64 + h * 32 + lq * 8]);
            }
#pragma unroll
            for (int i = 0; i < 4; ++i)
#pragma unroll
                for (int j = 0; j < 4; ++j)
                    acc[i][j] = __builtin_amdgcn_mfma_f32_16x16x32_bf16(af[i], bfr[j], acc[i][j], 0, 0, 0);
        }
    }

    const bool sig = (z == 2);
#pragma unroll
    for (int i = 0; i < 4; ++i)
#pragma unroll
        for (int j = 0; j < 4; ++j) {
            const int col = bn + wn + j * 16 + l15;
#pragma unroll
            for (int r = 0; r < 4; ++r) {
                const int row = bm + wm + i * 16 + lq * 4 + r;
                float val = acc[i][j][r];
                if (sig) val = 1.f / (1.f + __expf(-val));
                C[(size_t)row * 1024 + col] = f2bf(val);
            }
        }
}

// ---------------------------------------------------------------------------
// Wo GEMM: 128x128 tile, BK=64, 2-barrier.  C f32 = A bf16 @ Bt^T + Res.
// grid (64,8) = 512 blocks.
// ---------------------------------------------------------------------------
__global__ __launch_bounds__(256, 4) void gemm_wo(const unsigned short* __restrict__ A,
                                                  const unsigned short* __restrict__ Bt,
                                                  const float* __restrict__ Res,
                                                  float* __restrict__ C) {
    __shared__ __align__(16) unsigned short As[128 * 64];   // 16 KB
    __shared__ __align__(16) unsigned short Bs[128 * 64];   // 16 KB
    const int tid  = threadIdx.x;
    const int wave = tid >> 6, lane = tid & 63;
    const int wm = (wave >> 1) * 64, wn = (wave & 1) * 64;
    const int l15 = lane & 15, lq = lane >> 4;
    const int lrow = lane >> 3, lcol = (lane & 7) * 8;
    const int bm = blockIdx.x * 128, bn = blockIdx.y * 128;

    f32x4 acc[4][4] = {};

    for (int kt = 0; kt < 1024; kt += 64) {
        __syncthreads();
#pragma unroll
        for (int p = 0; p < 4; ++p) {
            const int r0 = p * 32 + wave * 8;
            gload_lds16(A  + (size_t)(bm + r0 + lrow) * 1024 + kt + lcol, &As[r0 * 64]);
            gload_lds16(Bt + (size_t)(bn + r0 + lrow) * 1024 + kt + lcol, &Bs[r0 * 64]);
        }
        __syncthreads();
#pragma unroll
        for (int h = 0; h < 2; ++h) {
            bf16x8 af[4], bfr[4];
#pragma unroll
            for (int i = 0; i < 4; ++i) {
                af[i]  = *(const bf16x8*)(&As[(wm + i * 16 + l15) * 64 + h * 32 + lq * 8]);
                bfr[i] = *(const bf16x8*)(&Bs[(wn + i * 16 + l15) * 64 + h * 32 + lq * 8]);
            }
#pragma unroll
            for (int i = 0; i < 4; ++i)
#pragma unroll
                for (int j = 0; j < 4; ++j)
                    acc[i][j] = __builtin_amdgcn_mfma_f32_16x16x32_bf16(af[i], bfr[j], acc[i][j], 0, 0, 0);
        }
    }

#pragma unroll
    for (int i = 0; i < 4; ++i)
#pragma unroll
        for (int j = 0; j < 4; ++j) {
            const int col = bn + wn + j * 16 + l15;
#pragma unroll
            for (int r = 0; r < 4; ++r) {
                const int row = bm + wm + i * 16 + lq * 4 + r;
                const size_t idx = (size_t)row * 1024 + col;
                C[idx] = acc[i][j][r] + Res[idx];
            }
        }
}

// ---------------------------------------------------------------------------
// WKV pass A: per (chunk, channel) stabilized local summary.
// NC chunks of length TT/NC.  grid NC*EE/256 x 256.
// ---------------------------------------------------------------------------
template <int NC>
__global__ void wkv_pass_a(const unsigned short* __restrict__ k,
                           const unsigned short* __restrict__ v,
                           const float* __restrict__ td,
                           float* __restrict__ Sa, float* __restrict__ Sb, float* __restrict__ Sp) {
    const int CL = TT / NC;
    const int gid = blockIdx.x * 256 + threadIdx.x;
    const int c = gid >> 10, e = gid & (EE - 1);
    const float w = -__expf(td[e]);
    float sa = 0.f, sb = 0.f, sp = -1e30f;
    const size_t base = (size_t)c * CL * EE + e;
    for (int i = 0; i < CL; ++i) {
        const size_t idx = base + (size_t)i * EE;
        const float kk = b2f(k[idx]), vv = b2f(v[idx]);
        const float q  = fmaf(w, (float)(CL - 1 - i), kk);
        const float p2 = fmaxf(sp, q);
        const float e1 = __expf(sp - p2), e2 = __expf(q - p2);
        sa = fmaf(e1, sa, e2 * vv);
        sb = fmaf(e1, sb, e2);
        sp = p2;
    }
    Sa[gid] = sa; Sb[gid] = sb; Sp[gid] = sp;
}

// ---------------------------------------------------------------------------
// WKV pass B (parallel): Kogge-Stone scan over NC=256 chunk summaries per
// channel.  grid EE blocks x 256 threads (block = one channel).
// ina/inb/inp layout: [e*NC + c].
// ---------------------------------------------------------------------------
__global__ void wkv_pass_b_par(const float* __restrict__ aa, const float* __restrict__ bb,
                               const float* __restrict__ pp, const float* __restrict__ td,
                               const float* __restrict__ x,
                               const float* __restrict__ Sa, const float* __restrict__ Sb,
                               const float* __restrict__ Sp,
                               float* __restrict__ ina, float* __restrict__ inb,
                               float* __restrict__ inp, float* __restrict__ outTail) {
    const int NC = 256, CL = TT / NC;
    const int e = blockIdx.x, c = threadIdx.x;
    __shared__ float sA[256], sB[256], sP[256];
    const float w = -__expf(td[e]);

    float a = Sa[c * EE + e], b = Sb[c * EE + e], p = Sp[c * EE + e];

    for (int s = 1; s < NC; s <<= 1) {
        sA[c] = a; sB[c] = b; sP[c] = p;
        __syncthreads();
        if (c >= s) {
            const float myLen = (float)(CL * min(c + 1, s));
            const float aL = sA[c - s], bL = sB[c - s], pL = sP[c - s];
            const float pLd = pL + w * myLen;
            const float pn  = fmaxf(pLd, p);
            const float e1  = __expf(pLd - pn), e2 = __expf(p - pn);
            a = fmaf(e1, aL, e2 * a);
            b = fmaf(e1, bL, e2 * b);
            p = pn;
        }
        __syncthreads();
    }

    sA[c] = a; sB[c] = b; sP[c] = p;
    __syncthreads();

    const float a0 = aa[e], b0 = bb[e], p0 = pp[e];
    float ea, eb, ep;
    if (c == 0) { ea = a0; eb = b0; ep = p0; }
    else {
        const float aL = sA[c - 1], bL = sB[c - 1], pL = sP[c - 1];
        const float p0d = p0 + w * (float)(c * CL);
        const float pn  = fmaxf(p0d, pL);
        const float e1  = __expf(p0d - pn), e2 = __expf(pL - pn);
        ea = fmaf(e1, a0, e2 * aL);
        eb = fmaf(e1, b0, e2 * bL);
        ep = pn;
    }
    ina[e * NC + c] = ea; inb[e * NC + c] = eb; inp[e * NC + c] = ep;

    if (c == NC - 1) {
        const float p0d = p0 + w * (float)TT;
        const float pn  = fmaxf(p0d, p);
        const float e1  = __expf(p0d - pn), e2 = __expf(p - pn);
        outTail[e]          = x[(size_t)(TT - 1) * EE + e];
        outTail[EE + e]     = fmaf(e1, a0, e2 * a);
        outTail[2 * EE + e] = fmaf(e1, b0, e2 * b);
        outTail[3 * EE + e] = pn;
    }
}

// ---------------------------------------------------------------------------
// WKV pass C: replay chunks from incoming state (ina layout [e*NC+c]);
// ry = sigmoid(r) in, y = sigmoid(r)*wkv out (in place).  grid NC*EE/256.
// ---------------------------------------------------------------------------
template <int NC>
__global__ void wkv_pass_c(const unsigned short* __restrict__ k,
                           const unsigned short* __restrict__ v,
                           const float* __restrict__ tf, const float* __restrict__ td,
                           const float* __restrict__ ina, const float* __restrict__ inb,
                           const float* __restrict__ inp,
                           unsigned short* ry) {
    const int CL = TT / NC;
    const int gid = blockIdx.x * 256 + threadIdx.x;
    const int c = gid >> 10, e = gid & (EE - 1);
    const float w = -__expf(td[e]);
    const float u = tf[e];
    float a = ina[e * NC + c], b = inb[e * NC + c], p = inp[e * NC + c];
    const size_t base = (size_t)c * CL * EE + e;
    for (int i = 0; i < CL; ++i) {
        const size_t idx = base + (size_t)i * EE;
        const float kk = b2f(k[idx]), vv = b2f(v[idx]);
        const float rr = b2f(ry[idx]);
        const float ww = u + kk;
        const float pq = fmaxf(p, ww);
        const float e1 = __expf(p - pq), e2 = __expf(ww - pq);
        const float wkv = fmaf(e1, a, e2 * vv) / fmaf(e1, b, e2);
        ry[idx] = f2bf(rr * wkv);
        const float ww2 = w + p;
        const float p2  = fmaxf(ww2, kk);
        const float e1b = __expf(ww2 - p2), e2b = __expf(kk - p2);
        a = fmaf(e1b, a, e2b * vv);
        b = fmaf(e1b, b, e2b);
        p = p2;
    }
}

// ---------------------------------------------------------------------------
// SMALL-path serial pass B (NC=128), ina layout [e*NC+c].
// ---------------------------------------------------------------------------
__global__ void wkv_pass_b_small(const float* __restrict__ aa, const float* __restrict__ bb,
                                 const float* __restrict__ pp, const float* __restrict__ td,
                                 const float* __restrict__ x,
                                 const float* __restrict__ Sa, const float* __restrict__ Sb,
                                 const float* __restrict__ Sp,
                                 float* __restrict__ ina, float* __restrict__ inb,
                                 float* __restrict__ inp, float* __restrict__ outTail) {
    const int NC = 128, CL = TT / NC;
    const int e = blockIdx.x * 256 + threadIdx.x;
    const float w  = -__expf(td[e]);
    const float wL = w * (float)CL;
    float a = aa[e], b = bb[e], p = pp[e];
    for (int c = 0; c < NC; ++c) {
        ina[e * NC + c] = a; inb[e * NC + c] = b; inp[e * NC + c] = p;
        const int idx = c * EE + e;
        const float sa = Sa[idx], sb = Sb[idx], sp = Sp[idx];
        const float pw = p + wL;
        const float p2 = fmaxf(pw, sp);
        const float e1 = __expf(pw - p2), e2 = __expf(sp - p2);
        a = fmaf(e1, a, e2 * sa);
        b = fmaf(e1, b, e2 * sb);
        p = p2;
    }
    outTail[e]          = x[(size_t)(TT - 1) * EE + e];
    outTail[EE + e]     = a;
    outTail[2 * EE + e] = b;
    outTail[3 * EE + e] = p;
}

// ---------------------------------------------------------------------------
// SMALL path (<75 MB): fused-mix k/v/r GEMM (round-3 structure).
// ---------------------------------------------------------------------------
__global__ __launch_bounds__(256, 4) void gemm_kvr(
        const float* __restrict__ X, const float* __restrict__ SX,
        const float* __restrict__ tmk, const float* __restrict__ tmv,
        const float* __restrict__ tmr,
        const unsigned short* __restrict__ Wkt, const unsigned short* __restrict__ Wvt,
        const unsigned short* __restrict__ Wrt,
        unsigned short* __restrict__ outK, unsigned short* __restrict__ outV,
        unsigned short* __restrict__ outR) {
    __shared__ __align__(16) unsigned short As[128 * LDSK];
    __shared__ __align__(16) unsigned short Bs[128 * LDSK];
    const int z = blockIdx.z;
    const float* TM = (z == 0) ? tmk : (z == 1) ? tmv : tmr;
    const unsigned short* Bt = (z == 0) ? Wkt : (z == 1) ? Wvt : Wrt;
    unsigned short* Cout = (z == 0) ? outK : (z == 1) ? outV : outR;

    const int tid  = threadIdx.x;
    const int wave = tid >> 6, lane = tid & 63;
    const int wm = (wave >> 1) * 64, wn = (wave & 1) * 64;
    const int l15 = lane & 15, lq = lane >> 4;
    const int bm = blockIdx.x * 128, bn = blockIdx.y * 128;

    f32x4 acc[4][4] = {};

    for (int kt = 0; kt < 1024; kt += 32) {
        __syncthreads();
#pragma unroll
        for (int p = 0; p < 2; ++p) {
            const int li  = p * 256 + tid;
            const int row = li >> 2, q = li & 3;
            const int e0  = kt + q * 8;
            {
                const int t = bm + row;
                const float* xr = X + (size_t)t * EE + e0;
                const float* pr = (t > 0) ? (X + (size_t)(t - 1) * EE + e0) : (SX + e0);
                float4 xa = *(const float4*)xr, xb = *(const float4*)(xr + 4);
                float4 pa = *(const float4*)pr, pb = *(const float4*)(pr + 4);
                float4 ma = *(const float4*)(TM + e0), mb = *(const float4*)(TM + e0 + 4);
                ushort4 lo, hi;
                lo.x = f2bf(fmaf(ma.x, xa.x - pa.x, pa.x));
                lo.y = f2bf(fmaf(ma.y, xa.y - pa.y, pa.y));
                lo.z = f2bf(fmaf(ma.z, xa.z - pa.z, pa.z));
                lo.w = f2bf(fmaf(ma.w, xa.w - pa.w, pa.w));
                hi.x = f2bf(fmaf(mb.x, xb.x - pb.x, pb.x));
                hi.y = f2bf(fmaf(mb.y, xb.y - pb.y, pb.y));
                hi.z = f2bf(fmaf(mb.z, xb.z - pb.z, pb.z));
                hi.w = f2bf(fmaf(mb.w, xb.w - pb.w, pb.w));
                *(ushort4*)(&As[row * LDSK + q * 8])     = lo;
                *(ushort4*)(&As[row * LDSK + q * 8 + 4]) = hi;
            }
            *(uint4*)(&Bs[row * LDSK + q * 8]) =
                *(const uint4*)(Bt + (size_t)(bn + row) * 1024 + e0);
        }
        __syncthreads();
        bf16x8 af[4], bfr[4];
#pragma unroll
        for (int i = 0; i < 4; ++i) {
            af[i]  = *(const bf16x8*)(&As[(wm + i * 16 + l15) * LDSK + lq * 8]);
            bfr[i] = *(const bf16x8*)(&Bs[(wn + i * 16 + l15) * LDSK + lq * 8]);
        }
#pragma unroll
        for (int i = 0; i < 4; ++i)
#pragma unroll
            for (int j = 0; j < 4; ++j)
                acc[i][j] = __builtin_amdgcn_mfma_f32_16x16x32_bf16(af[i], bfr[j], acc[i][j], 0, 0, 0);
    }

    const bool sig = (z == 2);
#pragma unroll
    for (int i = 0; i < 4; ++i)
#pragma unroll
        for (int j = 0; j < 4; ++j) {
            const int col = bn + wn + j * 16 + l15;
#pragma unroll
            for (int r = 0; r < 4; ++r) {
                const int row = bm + wm + i * 16 + lq * 4 + r;
                float val = acc[i][j][r];
                if (sig) val = 1.f / (1.f + __expf(-val));
                Cout[(size_t)row * 1024 + col] = f2bf(val);
            }
        }
}

// ---------------------------------------------------------------------------
extern "C" void kernel_launch(void* const* d_in, const int* in_sizes, int n_in,
                              void* d_out, int out_size, void* d_ws, size_t ws_size,
                              hipStream_t stream) {
    const float* x   = (const float*)d_in[0];
    const float* sx  = (const float*)d_in[1];
    const float* aa  = (const float*)d_in[2];
    const float* bb  = (const float*)d_in[3];
    const float* pp  = (const float*)d_in[4];
    const float* tf  = (const float*)d_in[5];
    const float* td  = (const float*)d_in[6];
    const float* tmk = (const float*)d_in[7];
    const float* tmv = (const float*)d_in[8];
    const float* tmr = (const float*)d_in[9];
    const float* Wk  = (const float*)d_in[10];
    const float* Wv  = (const float*)d_in[11];
    const float* Wr  = (const float*)d_in[12];
    const float* Wo  = (const float*)d_in[13];
    float* out = (float*)d_out;

    char* ws = (char*)d_ws;
    const size_t MB = 1ull << 20;

    unsigned short* Wkt = (unsigned short*)(ws + 0 * MB);   // 2 MB each
    unsigned short* Wvt = (unsigned short*)(ws + 2 * MB);
    unsigned short* Wrt = (unsigned short*)(ws + 4 * MB);
    unsigned short* Wot = (unsigned short*)(ws + 6 * MB);

    if (ws_size >= 75 * MB) {
        // ws: [0:8] Wt | [8:24] rxb (scan bufs overlay after kvr3) |
        //     [24:40] kf | [40:56] ry | [56:72] vf
        unsigned short* rxb = (unsigned short*)(ws + 8 * MB);
        unsigned short* kf  = (unsigned short*)(ws + 24 * MB);
        unsigned short* ry  = (unsigned short*)(ws + 40 * MB);
        unsigned short* vf  = (unsigned short*)(ws + 56 * MB);
        // scan buffers: 6 x 1 MB, overlaying the dead rxb region [8:14]
        float* Sa  = (float*)(ws + 8 * MB);
        float* Sb  = (float*)(ws + 9 * MB);
        float* Sp  = (float*)(ws + 10 * MB);
        float* ina = (float*)(ws + 11 * MB);
        float* inb = (float*)(ws + 12 * MB);
        float* inp = (float*)(ws + 13 * MB);
        unsigned short* kxb = (unsigned short*)d_out;                   // d_out scratch
        unsigned short* vxb = (unsigned short*)d_out + (size_t)TT * EE;

        prep_kernel<<<12288, 256, 0, stream>>>(Wk, Wv, Wr, Wo, Wkt, Wvt, Wrt, Wot,
                                               x, sx, tmk, tmv, tmr, kxb, vxb, rxb);
        gemm_kvr3<<<dim3(64, 8, 3), 256, 0, stream>>>(kxb, vxb, rxb, Wkt, Wvt, Wrt,
                                                      kf, vf, ry);
        wkv_pass_a<256><<<(256 * EE) / 256, 256, 0, stream>>>(kf, vf, td, Sa, Sb, Sp);
        wkv_pass_b_par<<<EE, 256, 0, stream>>>(aa, bb, pp, td, x, Sa, Sb, Sp,
                                               ina, inb, inp, out + (size_t)TT * EE);
        wkv_pass_c<256><<<(256 * EE) / 256, 256, 0, stream>>>(kf, vf, tf, td,
                                                              ina, inb, inp, ry);
        gemm_wo<<<dim3(64, 8), 256, 0, stream>>>(ry, Wot, x, out);
    } else {
        // 27 MB proven fallback (NC=128)
        unsigned short* ry = (unsigned short*)(ws + 8 * MB);
        char* scan = ws + 24 * MB;
        const size_t QK = (size_t)128 * EE * sizeof(float);  // 512 KB
        float* Sa  = (float*)(scan);
        float* Sb  = (float*)(scan + QK);
        float* Sp  = (float*)(scan + 2 * QK);
        float* ina = (float*)(scan + 3 * QK);
        float* inb = (float*)(scan + 4 * QK);
        float* inp = (float*)(scan + 5 * QK);
        unsigned short* kf = (unsigned short*)d_out;
        unsigned short* vf = (unsigned short*)d_out + (size_t)TT * EE;

        wt_kernel<<<dim3(32, 32, 4), dim3(32, 8), 0, stream>>>(Wk, Wv, Wr, Wo, Wkt, Wvt, Wrt, Wot);
        gemm_kvr<<<dim3(64, 8, 3), 256, 0, stream>>>(x, sx, tmk, tmv, tmr,
                                                     Wkt, Wvt, Wrt, kf, vf, ry);
        wkv_pass_a<128><<<(128 * EE) / 256, 256, 0, stream>>>(kf, vf, td, Sa, Sb, Sp);
        wkv_pass_b_small<<<4, 256, 0, stream>>>(aa, bb, pp, td, x, Sa, Sb, Sp,
                                                ina, inb, inp, out + (size_t)TT * EE);
        wkv_pass_c<128><<<(128 * EE) / 256, 256, 0, stream>>>(kf, vf, tf, td,
                                                              ina, inb, inp, ry);
        gemm_wo<<<dim3(64, 8), 256, 0, stream>>>(ry, Wot, x, out);
    }
}

// Round 9
// 243.374 us; speedup vs baseline: 1.2080x; 1.0412x over previous
//
#include <hip/hip_runtime.h>
#include <cstdint>
#include <cstddef>

typedef __bf16 bf16x8 __attribute__((ext_vector_type(8)));
typedef float  f32x4  __attribute__((ext_vector_type(4)));

#define TT 8192
#define EE 1024
#define LDSK 40    // small-path padded LDS stride (shorts)

__device__ __forceinline__ unsigned short f2bf(float f) {
    union { float f; unsigned int u; } v; v.f = f;
    unsigned int r = v.u + 0x7FFFu + ((v.u >> 16) & 1u);
    return (unsigned short)(r >> 16);
}
__device__ __forceinline__ float b2f(unsigned int h) {
    union { unsigned int u; float f; } v; v.u = h << 16; return v.f;
}
__device__ __forceinline__ void gload_lds16(const void* g, void* l) {
    __builtin_amdgcn_global_load_lds((__attribute__((address_space(1))) void*)g,
                                     (__attribute__((address_space(3))) void*)l, 16, 0, 0);
}

// ---------------------------------------------------------------------------
// Standalone W transpose (small path). grid (32,32,4), block (32,8).
// ---------------------------------------------------------------------------
__global__ void wt_kernel(const float* __restrict__ Wk, const float* __restrict__ Wv,
                          const float* __restrict__ Wr, const float* __restrict__ Wo,
                          unsigned short* __restrict__ Tk, unsigned short* __restrict__ Tv,
                          unsigned short* __restrict__ Tr, unsigned short* __restrict__ To) {
    __shared__ float tile[32][33];
    const float* W; unsigned short* D;
    switch (blockIdx.z) {
        case 0:  W = Wk; D = Tk; break;
        case 1:  W = Wv; D = Tv; break;
        case 2:  W = Wr; D = Tr; break;
        default: W = Wo; D = To; break;
    }
    const int bx = blockIdx.x * 32, by = blockIdx.y * 32;
    const int tx = threadIdx.x, ty = threadIdx.y;
#pragma unroll
    for (int r = 0; r < 4; ++r)
        tile[ty + 8 * r][tx] = W[(size_t)(by + ty + 8 * r) * EE + bx + tx];
    __syncthreads();
#pragma unroll
    for (int r = 0; r < 4; ++r)
        D[(size_t)(bx + ty + 8 * r) * EE + by + tx] = f2bf(tile[tx][ty + 8 * r]);
}

// ---------------------------------------------------------------------------
// Fused prep: blocks [0,4096) transpose 4 Ws; blocks [4096,12288) token-shift
// mix -> bf16 kx/vx/rx.  1D grid 12288, block 256.
// ---------------------------------------------------------------------------
__global__ void prep_kernel(const float* __restrict__ Wk, const float* __restrict__ Wv,
                            const float* __restrict__ Wr, const float* __restrict__ Wo,
                            unsigned short* __restrict__ Tk, unsigned short* __restrict__ Tv,
                            unsigned short* __restrict__ Tr, unsigned short* __restrict__ To,
                            const float* __restrict__ x, const float* __restrict__ sx,
                            const float* __restrict__ tmk, const float* __restrict__ tmv,
                            const float* __restrict__ tmr,
                            unsigned short* __restrict__ kxb, unsigned short* __restrict__ vxb,
                            unsigned short* __restrict__ rxb) {
    const int bid = blockIdx.x;
    if (bid < 4096) {
        __shared__ float tile[32][33];
        const int z = bid >> 10;
        const float* W; unsigned short* D;
        switch (z) {
            case 0:  W = Wk; D = Tk; break;
            case 1:  W = Wv; D = Tv; break;
            case 2:  W = Wr; D = Tr; break;
            default: W = Wo; D = To; break;
        }
        const int by = ((bid >> 5) & 31) * 32, bx = (bid & 31) * 32;
        const int tx = threadIdx.x & 31, ty = threadIdx.x >> 5;
#pragma unroll
        for (int r = 0; r < 4; ++r)
            tile[ty + 8 * r][tx] = W[(size_t)(by + ty + 8 * r) * EE + bx + tx];
        __syncthreads();
#pragma unroll
        for (int r = 0; r < 4; ++r)
            D[(size_t)(bx + ty + 8 * r) * EE + by + tx] = f2bf(tile[tx][ty + 8 * r]);
    } else {
        const int gid  = (bid - 4096) * 256 + threadIdx.x;
        const int base = gid * 4;
        const int t = base >> 10;
        const int e = base & (EE - 1);
        float4 xv = *(const float4*)(x + base);
        float4 pv = (t > 0) ? *(const float4*)(x + base - EE) : *(const float4*)(sx + e);
        float4 mk = *(const float4*)(tmk + e);
        float4 mv = *(const float4*)(tmv + e);
        float4 mr = *(const float4*)(tmr + e);
        ushort4 ko, vo, ro;
        ko.x = f2bf(fmaf(mk.x, xv.x - pv.x, pv.x));
        ko.y = f2bf(fmaf(mk.y, xv.y - pv.y, pv.y));
        ko.z = f2bf(fmaf(mk.z, xv.z - pv.z, pv.z));
        ko.w = f2bf(fmaf(mk.w, xv.w - pv.w, pv.w));
        vo.x = f2bf(fmaf(mv.x, xv.x - pv.x, pv.x));
        vo.y = f2bf(fmaf(mv.y, xv.y - pv.y, pv.y));
        vo.z = f2bf(fmaf(mv.z, xv.z - pv.z, pv.z));
        vo.w = f2bf(fmaf(mv.w, xv.w - pv.w, pv.w));
        ro.x = f2bf(fmaf(mr.x, xv.x - pv.x, pv.x));
        ro.y = f2bf(fmaf(mr.y, xv.y - pv.y, pv.y));
        ro.z = f2bf(fmaf(mr.z, xv.z - pv.z, pv.z));
        ro.w = f2bf(fmaf(mr.w, xv.w - pv.w, pv.w));
        *(ushort4*)(kxb + base) = ko;
        *(ushort4*)(vxb + base) = vo;
        *(ushort4*)(rxb + base) = ro;
    }
}

// ---------------------------------------------------------------------------
// 128x128-tile bf16 GEMM, BK=64, 2-barrier K-loop (16 iters), XOR-swizzled
// LDS (16B group g of row r lives at g^(r&7) -> conflict-free ds_read_b128).
// 3 operand sets via blockIdx.z (z==2 -> sigmoid).  grid (64,8,3).
// ---------------------------------------------------------------------------
__global__ __launch_bounds__(256, 4) void gemm_kvr3(
        const unsigned short* __restrict__ kxb, const unsigned short* __restrict__ vxb,
        const unsigned short* __restrict__ rxb,
        const unsigned short* __restrict__ Wkt, const unsigned short* __restrict__ Wvt,
        const unsigned short* __restrict__ Wrt,
        unsigned short* __restrict__ kf, unsigned short* __restrict__ vf,
        unsigned short* __restrict__ ry) {
    __shared__ __align__(16) unsigned short As[128 * 64];   // 16 KB
    __shared__ __align__(16) unsigned short Bs[128 * 64];   // 16 KB
    const int z = blockIdx.z;
    const unsigned short* A  = (z == 0) ? kxb : (z == 1) ? vxb : rxb;
    const unsigned short* Bt = (z == 0) ? Wkt : (z == 1) ? Wvt : Wrt;
    unsigned short* C        = (z == 0) ? kf  : (z == 1) ? vf  : ry;

    const int tid  = threadIdx.x;
    const int wave = tid >> 6, lane = tid & 63;
    const int wm = (wave >> 1) * 64, wn = (wave & 1) * 64;
    const int l15 = lane & 15, lq = lane >> 4;
    const int lrow = lane >> 3;                          // 8 lanes/row, 8 rows/instr
    const int lcolg = (((lane & 7) ^ lrow) & 7) * 8;     // swizzled global col group
    const int sw = l15 & 7;                              // read-side swizzle key
    const int bm = blockIdx.x * 128, bn = blockIdx.y * 128;

    f32x4 acc[4][4] = {};

    for (int kt = 0; kt < 1024; kt += 64) {
        __syncthreads();
#pragma unroll
        for (int p = 0; p < 4; ++p) {
            const int r0 = p * 32 + wave * 8;
            gload_lds16(A  + (size_t)(bm + r0 + lrow) * 1024 + kt + lcolg, &As[r0 * 64]);
            gload_lds16(Bt + (size_t)(bn + r0 + lrow) * 1024 + kt + lcolg, &Bs[r0 * 64]);
        }
        __syncthreads();
#pragma unroll
        for (int h = 0; h < 2; ++h) {
            bf16x8 af[4], bfr[4];
#pragma unroll
            for (int i = 0; i < 4; ++i) {
                const int g = ((h * 4 + lq) ^ sw) * 8;
                af[i]  = *(const bf16x8*)(&As[(wm + i * 16 + l15) * 64 + g]);
                bfr[i] = *(const bf16x8*)(&Bs[(wn + i * 16 + l15) * 64 + g]);
            }
#pragma unroll
            for (int i = 0; i < 4; ++i)
#pragma unroll
                for (int j = 0; j < 4; ++j)
                    acc[i][j] = __builtin_amdgcn_mfma_f32_16x16x32_bf16(af[i], bfr[j], acc[i][j], 0, 0, 0);
        }
    }

    const bool sig = (z == 2);
#pragma unroll
    for (int i = 0; i < 4; ++i)
#pragma unroll
        for (int j = 0; j < 4; ++j) {
            const int col = bn + wn + j * 16 + l15;
#pragma unroll
            for (int r = 0; r < 4; ++r) {
                const int row = bm + wm + i * 16 + lq * 4 + r;
                float val = acc[i][j][r];
                if (sig) val = 1.f / (1.f + __expf(-val));
                C[(size_t)row * 1024 + col] = f2bf(val);
            }
        }
}

// ---------------------------------------------------------------------------
// Wo GEMM: 128x128 tile, BK=64, XOR-swizzled LDS.  C f32 = A bf16 @ Bt^T + Res.
// grid (64,8) = 512 blocks.
// ---------------------------------------------------------------------------
__global__ __launch_bounds__(256, 4) void gemm_wo(const unsigned short* __restrict__ A,
                                                  const unsigned short* __restrict__ Bt,
                                                  const float* __restrict__ Res,
                                                  float* __restrict__ C) {
    __shared__ __align__(16) unsigned short As[128 * 64];   // 16 KB
    __shared__ __align__(16) unsigned short Bs[128 * 64];   // 16 KB
    const int tid  = threadIdx.x;
    const int wave = tid >> 6, lane = tid & 63;
    const int wm = (wave >> 1) * 64, wn = (wave & 1) * 64;
    const int l15 = lane & 15, lq = lane >> 4;
    const int lrow = lane >> 3;
    const int lcolg = (((lane & 7) ^ lrow) & 7) * 8;
    const int sw = l15 & 7;
    const int bm = blockIdx.x * 128, bn = blockIdx.y * 128;

    f32x4 acc[4][4] = {};

    for (int kt = 0; kt < 1024; kt += 64) {
        __syncthreads();
#pragma unroll
        for (int p = 0; p < 4; ++p) {
            const int r0 = p * 32 + wave * 8;
            gload_lds16(A  + (size_t)(bm + r0 + lrow) * 1024 + kt + lcolg, &As[r0 * 64]);
            gload_lds16(Bt + (size_t)(bn + r0 + lrow) * 1024 + kt + lcolg, &Bs[r0 * 64]);
        }
        __syncthreads();
#pragma unroll
        for (int h = 0; h < 2; ++h) {
            bf16x8 af[4], bfr[4];
#pragma unroll
            for (int i = 0; i < 4; ++i) {
                const int g = ((h * 4 + lq) ^ sw) * 8;
                af[i]  = *(const bf16x8*)(&As[(wm + i * 16 + l15) * 64 + g]);
                bfr[i] = *(const bf16x8*)(&Bs[(wn + i * 16 + l15) * 64 + g]);
            }
#pragma unroll
            for (int i = 0; i < 4; ++i)
#pragma unroll
                for (int j = 0; j < 4; ++j)
                    acc[i][j] = __builtin_amdgcn_mfma_f32_16x16x32_bf16(af[i], bfr[j], acc[i][j], 0, 0, 0);
        }
    }

#pragma unroll
    for (int i = 0; i < 4; ++i)
#pragma unroll
        for (int j = 0; j < 4; ++j) {
            const int col = bn + wn + j * 16 + l15;
#pragma unroll
            for (int r = 0; r < 4; ++r) {
                const int row = bm + wm + i * 16 + lq * 4 + r;
                const size_t idx = (size_t)row * 1024 + col;
                C[idx] = acc[i][j][r] + Res[idx];
            }
        }
}

// ---------------------------------------------------------------------------
// WKV pass A: per (chunk, channel) stabilized local summary.
// NC chunks of length TT/NC.  grid NC*EE/256 x 256.
// ---------------------------------------------------------------------------
template <int NC>
__global__ void wkv_pass_a(const unsigned short* __restrict__ k,
                           const unsigned short* __restrict__ v,
                           const float* __restrict__ td,
                           float* __restrict__ Sa, float* __restrict__ Sb, float* __restrict__ Sp) {
    const int CL = TT / NC;
    const int gid = blockIdx.x * 256 + threadIdx.x;
    const int c = gid >> 10, e = gid & (EE - 1);
    const float w = -__expf(td[e]);
    float sa = 0.f, sb = 0.f, sp = -1e30f;
    const size_t base = (size_t)c * CL * EE + e;
    for (int i = 0; i < CL; ++i) {
        const size_t idx = base + (size_t)i * EE;
        const float kk = b2f(k[idx]), vv = b2f(v[idx]);
        const float q  = fmaf(w, (float)(CL - 1 - i), kk);
        const float p2 = fmaxf(sp, q);
        const float e1 = __expf(sp - p2), e2 = __expf(q - p2);
        sa = fmaf(e1, sa, e2 * vv);
        sb = fmaf(e1, sb, e2);
        sp = p2;
    }
    Sa[gid] = sa; Sb[gid] = sb; Sp[gid] = sp;
}

// ---------------------------------------------------------------------------
// WKV pass B (parallel): Kogge-Stone scan over NC=256 chunk summaries per
// channel.  grid EE blocks x 256 threads.  ina/inb/inp layout: [e*NC + c].
// ---------------------------------------------------------------------------
__global__ void wkv_pass_b_par(const float* __restrict__ aa, const float* __restrict__ bb,
                               const float* __restrict__ pp, const float* __restrict__ td,
                               const float* __restrict__ x,
                               const float* __restrict__ Sa, const float* __restrict__ Sb,
                               const float* __restrict__ Sp,
                               float* __restrict__ ina, float* __restrict__ inb,
                               float* __restrict__ inp, float* __restrict__ outTail) {
    const int NC = 256, CL = TT / NC;
    const int e = blockIdx.x, c = threadIdx.x;
    __shared__ float sA[256], sB[256], sP[256];
    const float w = -__expf(td[e]);

    float a = Sa[c * EE + e], b = Sb[c * EE + e], p = Sp[c * EE + e];

    for (int s = 1; s < NC; s <<= 1) {
        sA[c] = a; sB[c] = b; sP[c] = p;
        __syncthreads();
        if (c >= s) {
            const float myLen = (float)(CL * min(c + 1, s));
            const float aL = sA[c - s], bL = sB[c - s], pL = sP[c - s];
            const float pLd = pL + w * myLen;
            const float pn  = fmaxf(pLd, p);
            const float e1  = __expf(pLd - pn), e2 = __expf(p - pn);
            a = fmaf(e1, aL, e2 * a);
            b = fmaf(e1, bL, e2 * b);
            p = pn;
        }
        __syncthreads();
    }

    sA[c] = a; sB[c] = b; sP[c] = p;
    __syncthreads();

    const float a0 = aa[e], b0 = bb[e], p0 = pp[e];
    float ea, eb, ep;
    if (c == 0) { ea = a0; eb = b0; ep = p0; }
    else {
        const float aL = sA[c - 1], bL = sB[c - 1], pL = sP[c - 1];
        const float p0d = p0 + w * (float)(c * CL);
        const float pn  = fmaxf(p0d, pL);
        const float e1  = __expf(p0d - pn), e2 = __expf(pL - pn);
        ea = fmaf(e1, a0, e2 * aL);
        eb = fmaf(e1, b0, e2 * bL);
        ep = pn;
    }
    ina[e * NC + c] = ea; inb[e * NC + c] = eb; inp[e * NC + c] = ep;

    if (c == NC - 1) {
        const float p0d = p0 + w * (float)TT;
        const float pn  = fmaxf(p0d, p);
        const float e1  = __expf(p0d - pn), e2 = __expf(p - pn);
        outTail[e]          = x[(size_t)(TT - 1) * EE + e];
        outTail[EE + e]     = fmaf(e1, a0, e2 * a);
        outTail[2 * EE + e] = fmaf(e1, b0, e2 * b);
        outTail[3 * EE + e] = pn;
    }
}

// ---------------------------------------------------------------------------
// WKV pass C: replay chunks from incoming state (ina layout [e*NC+c]);
// ry = sigmoid(r) in, y = sigmoid(r)*wkv out (in place).  grid NC*EE/256.
// ---------------------------------------------------------------------------
template <int NC>
__global__ void wkv_pass_c(const unsigned short* __restrict__ k,
                           const unsigned short* __restrict__ v,
                           const float* __restrict__ tf, const float* __restrict__ td,
                           const float* __restrict__ ina, const float* __restrict__ inb,
                           const float* __restrict__ inp,
                           unsigned short* ry) {
    const int CL = TT / NC;
    const int gid = blockIdx.x * 256 + threadIdx.x;
    const int c = gid >> 10, e = gid & (EE - 1);
    const float w = -__expf(td[e]);
    const float u = tf[e];
    float a = ina[e * NC + c], b = inb[e * NC + c], p = inp[e * NC + c];
    const size_t base = (size_t)c * CL * EE + e;
    for (int i = 0; i < CL; ++i) {
        const size_t idx = base + (size_t)i * EE;
        const float kk = b2f(k[idx]), vv = b2f(v[idx]);
        const float rr = b2f(ry[idx]);
        const float ww = u + kk;
        const float pq = fmaxf(p, ww);
        const float e1 = __expf(p - pq), e2 = __expf(ww - pq);
        const float wkv = fmaf(e1, a, e2 * vv) / fmaf(e1, b, e2);
        ry[idx] = f2bf(rr * wkv);
        const float ww2 = w + p;
        const float p2  = fmaxf(ww2, kk);
        const float e1b = __expf(ww2 - p2), e2b = __expf(kk - p2);
        a = fmaf(e1b, a, e2b * vv);
        b = fmaf(e1b, b, e2b);
        p = p2;
    }
}

// ---------------------------------------------------------------------------
// SMALL-path serial pass B (NC=128), ina layout [e*NC+c].
// ---------------------------------------------------------------------------
__global__ void wkv_pass_b_small(const float* __restrict__ aa, const float* __restrict__ bb,
                                 const float* __restrict__ pp, const float* __restrict__ td,
                                 const float* __restrict__ x,
                                 const float* __restrict__ Sa, const float* __restrict__ Sb,
                                 const float* __restrict__ Sp,
                                 float* __restrict__ ina, float* __restrict__ inb,
                                 float* __restrict__ inp, float* __restrict__ outTail) {
    const int NC = 128, CL = TT / NC;
    const int e = blockIdx.x * 256 + threadIdx.x;
    const float w  = -__expf(td[e]);
    const float wL = w * (float)CL;
    float a = aa[e], b = bb[e], p = pp[e];
    for (int c = 0; c < NC; ++c) {
        ina[e * NC + c] = a; inb[e * NC + c] = b; inp[e * NC + c] = p;
        const int idx = c * EE + e;
        const float sa = Sa[idx], sb = Sb[idx], sp = Sp[idx];
        const float pw = p + wL;
        const float p2 = fmaxf(pw, sp);
        const float e1 = __expf(pw - p2), e2 = __expf(sp - p2);
        a = fmaf(e1, a, e2 * sa);
        b = fmaf(e1, b, e2 * sb);
        p = p2;
    }
    outTail[e]          = x[(size_t)(TT - 1) * EE + e];
    outTail[EE + e]     = a;
    outTail[2 * EE + e] = b;
    outTail[3 * EE + e] = p;
}

// ---------------------------------------------------------------------------
// SMALL path (<75 MB): fused-mix k/v/r GEMM (round-3 structure).
// ---------------------------------------------------------------------------
__global__ __launch_bounds__(256, 4) void gemm_kvr(
        const float* __restrict__ X, const float* __restrict__ SX,
        const float* __restrict__ tmk, const float* __restrict__ tmv,
        const float* __restrict__ tmr,
        const unsigned short* __restrict__ Wkt, const unsigned short* __restrict__ Wvt,
        const unsigned short* __restrict__ Wrt,
        unsigned short* __restrict__ outK, unsigned short* __restrict__ outV,
        unsigned short* __restrict__ outR) {
    __shared__ __align__(16) unsigned short As[128 * LDSK];
    __shared__ __align__(16) unsigned short Bs[128 * LDSK];
    const int z = blockIdx.z;
    const float* TM = (z == 0) ? tmk : (z == 1) ? tmv : tmr;
    const unsigned short* Bt = (z == 0) ? Wkt : (z == 1) ? Wvt : Wrt;
    unsigned short* Cout = (z == 0) ? outK : (z == 1) ? outV : outR;

    const int tid  = threadIdx.x;
    const int wave = tid >> 6, lane = tid & 63;
    const int wm = (wave >> 1) * 64, wn = (wave & 1) * 64;
    const int l15 = lane & 15, lq = lane >> 4;
    const int bm = blockIdx.x * 128, bn = blockIdx.y * 128;

    f32x4 acc[4][4] = {};

    for (int kt = 0; kt < 1024; kt += 32) {
        __syncthreads();
#pragma unroll
        for (int p = 0; p < 2; ++p) {
            const int li  = p * 256 + tid;
            const int row = li >> 2, q = li & 3;
            const int e0  = kt + q * 8;
            {
                const int t = bm + row;
                const float* xr = X + (size_t)t * EE + e0;
                const float* pr = (t > 0) ? (X + (size_t)(t - 1) * EE + e0) : (SX + e0);
                float4 xa = *(const float4*)xr, xb = *(const float4*)(xr + 4);
                float4 pa = *(const float4*)pr, pb = *(const float4*)(pr + 4);
                float4 ma = *(const float4*)(TM + e0), mb = *(const float4*)(TM + e0 + 4);
                ushort4 lo, hi;
                lo.x = f2bf(fmaf(ma.x, xa.x - pa.x, pa.x));
                lo.y = f2bf(fmaf(ma.y, xa.y - pa.y, pa.y));
                lo.z = f2bf(fmaf(ma.z, xa.z - pa.z, pa.z));
                lo.w = f2bf(fmaf(ma.w, xa.w - pa.w, pa.w));
                hi.x = f2bf(fmaf(mb.x, xb.x - pb.x, pb.x));
                hi.y = f2bf(fmaf(mb.y, xb.y - pb.y, pb.y));
                hi.z = f2bf(fmaf(mb.z, xb.z - pb.z, pb.z));
                hi.w = f2bf(fmaf(mb.w, xb.w - pb.w, pb.w));
                *(ushort4*)(&As[row * LDSK + q * 8])     = lo;
                *(ushort4*)(&As[row * LDSK + q * 8 + 4]) = hi;
            }
            *(uint4*)(&Bs[row * LDSK + q * 8]) =
                *(const uint4*)(Bt + (size_t)(bn + row) * 1024 + e0);
        }
        __syncthreads();
        bf16x8 af[4], bfr[4];
#pragma unroll
        for (int i = 0; i < 4; ++i) {
            af[i]  = *(const bf16x8*)(&As[(wm + i * 16 + l15) * LDSK + lq * 8]);
            bfr[i] = *(const bf16x8*)(&Bs[(wn + i * 16 + l15) * LDSK + lq * 8]);
        }
#pragma unroll
        for (int i = 0; i < 4; ++i)
#pragma unroll
            for (int j = 0; j < 4; ++j)
                acc[i][j] = __builtin_amdgcn_mfma_f32_16x16x32_bf16(af[i], bfr[j], acc[i][j], 0, 0, 0);
    }

    const bool sig = (z == 2);
#pragma unroll
    for (int i = 0; i < 4; ++i)
#pragma unroll
        for (int j = 0; j < 4; ++j) {
            const int col = bn + wn + j * 16 + l15;
#pragma unroll
            for (int r = 0; r < 4; ++r) {
                const int row = bm + wm + i * 16 + lq * 4 + r;
                float val = acc[i][j][r];
                if (sig) val = 1.f / (1.f + __expf(-val));
                Cout[(size_t)row * 1024 + col] = f2bf(val);
            }
        }
}

// ---------------------------------------------------------------------------
extern "C" void kernel_launch(void* const* d_in, const int* in_sizes, int n_in,
                              void* d_out, int out_size, void* d_ws, size_t ws_size,
                              hipStream_t stream) {
    const float* x   = (const float*)d_in[0];
    const float* sx  = (const float*)d_in[1];
    const float* aa  = (const float*)d_in[2];
    const float* bb  = (const float*)d_in[3];
    const float* pp  = (const float*)d_in[4];
    const float* tf  = (const float*)d_in[5];
    const float* td  = (const float*)d_in[6];
    const float* tmk = (const float*)d_in[7];
    const float* tmv = (const float*)d_in[8];
    const float* tmr = (const float*)d_in[9];
    const float* Wk  = (const float*)d_in[10];
    const float* Wv  = (const float*)d_in[11];
    const float* Wr  = (const float*)d_in[12];
    const float* Wo  = (const float*)d_in[13];
    float* out = (float*)d_out;

    char* ws = (char*)d_ws;
    const size_t MB = 1ull << 20;

    unsigned short* Wkt = (unsigned short*)(ws + 0 * MB);   // 2 MB each
    unsigned short* Wvt = (unsigned short*)(ws + 2 * MB);
    unsigned short* Wrt = (unsigned short*)(ws + 4 * MB);
    unsigned short* Wot = (unsigned short*)(ws + 6 * MB);

    if (ws_size >= 75 * MB) {
        // ws: [0:8] Wt | [8:24] rxb (scan bufs overlay after kvr3) |
        //     [24:40] kf | [40:56] ry | [56:72] vf
        unsigned short* rxb = (unsigned short*)(ws + 8 * MB);
        unsigned short* kf  = (unsigned short*)(ws + 24 * MB);
        unsigned short* ry  = (unsigned short*)(ws + 40 * MB);
        unsigned short* vf  = (unsigned short*)(ws + 56 * MB);
        // scan buffers: 6 x 1 MB, overlaying the dead rxb region [8:14]
        float* Sa  = (float*)(ws + 8 * MB);
        float* Sb  = (float*)(ws + 9 * MB);
        float* Sp  = (float*)(ws + 10 * MB);
        float* ina = (float*)(ws + 11 * MB);
        float* inb = (float*)(ws + 12 * MB);
        float* inp = (float*)(ws + 13 * MB);
        unsigned short* kxb = (unsigned short*)d_out;                   // d_out scratch
        unsigned short* vxb = (unsigned short*)d_out + (size_t)TT * EE;

        prep_kernel<<<12288, 256, 0, stream>>>(Wk, Wv, Wr, Wo, Wkt, Wvt, Wrt, Wot,
                                               x, sx, tmk, tmv, tmr, kxb, vxb, rxb);
        gemm_kvr3<<<dim3(64, 8, 3), 256, 0, stream>>>(kxb, vxb, rxb, Wkt, Wvt, Wrt,
                                                      kf, vf, ry);
        wkv_pass_a<256><<<(256 * EE) / 256, 256, 0, stream>>>(kf, vf, td, Sa, Sb, Sp);
        wkv_pass_b_par<<<EE, 256, 0, stream>>>(aa, bb, pp, td, x, Sa, Sb, Sp,
                                               ina, inb, inp, out + (size_t)TT * EE);
        wkv_pass_c<256><<<(256 * EE) / 256, 256, 0, stream>>>(kf, vf, tf, td,
                                                              ina, inb, inp, ry);
        gemm_wo<<<dim3(64, 8), 256, 0, stream>>>(ry, Wot, x, out);
    } else {
        // 27 MB proven fallback (NC=128)
        unsigned short* ry = (unsigned short*)(ws + 8 * MB);
        char* scan = ws + 24 * MB;
        const size_t QK = (size_t)128 * EE * sizeof(float);  // 512 KB
        float* Sa  = (float*)(scan);
        float* Sb  = (float*)(scan + QK);
        float* Sp  = (float*)(scan + 2 * QK);
        float* ina = (float*)(scan + 3 * QK);
        float* inb = (float*)(scan + 4 * QK);
        float* inp = (float*)(scan + 5 * QK);
        unsigned short* kf = (unsigned short*)d_out;
        unsigned short* vf = (unsigned short*)d_out + (size_t)TT * EE;

        wt_kernel<<<dim3(32, 32, 4), dim3(32, 8), 0, stream>>>(Wk, Wv, Wr, Wo, Wkt, Wvt, Wrt, Wot);
        gemm_kvr<<<dim3(64, 8, 3), 256, 0, stream>>>(x, sx, tmk, tmv, tmr,
                                                     Wkt, Wvt, Wrt, kf, vf, ry);
        wkv_pass_a<128><<<(128 * EE) / 256, 256, 0, stream>>>(kf, vf, td, Sa, Sb, Sp);
        wkv_pass_b_small<<<4, 256, 0, stream>>>(aa, bb, pp, td, x, Sa, Sb, Sp,
                                                ina, inb, inp, out + (size_t)TT * EE);
        wkv_pass_c<128><<<(128 * EE) / 256, 256, 0, stream>>>(kf, vf, tf, td,
                                                              ina, inb, inp, ry);
        gemm_wo<<<dim3(64, 8), 256, 0, stream>>>(ry, Wot, x, out);
    }
}